// Round 4
// baseline (165.535 us; speedup 1.0000x reference)
//
#include <hip/hip_runtime.h>
#include <math.h>

constexpr int kNpts   = 72;
constexpr int kPriors = 192;
constexpr int kLanes  = 4;
constexpr int kBatch  = 512;
constexpr int kStages = 3;
constexpr int kD      = 6 + kNpts;            // 78
constexpr int kChunkRows = 64;
constexpr int kChunkF = kChunkRows * kD;      // 4992 floats = 19968 B
constexpr int kChunkV4 = kChunkF / 4;         // 1248 float4

typedef unsigned long long u64;

__device__ __forceinline__ float smoothL1(float x) {
  float ax = fabsf(x);
  return ax < 1.0f ? 0.5f * x * x : ax - 0.5f;
}

// monotone map float -> uint32 (ascending order preserved, handles +/-inf)
__device__ __forceinline__ unsigned ordF(float f) {
  unsigned b = __float_as_uint(f);
  return (b & 0x80000000u) ? ~b : (b | 0x80000000u);
}

__device__ __forceinline__ void cswapA(u64& a, u64& b) {        // ascending
  if (b < a) { u64 t = a; a = b; b = t; }
}
__device__ __forceinline__ void cswapD(float& a, float& b) {    // descending
  if (b > a) { float t = a; a = b; b = t; }
}
__device__ __forceinline__ u64 umin64(u64 a, u64 b) { return a < b ? a : b; }
__device__ __forceinline__ u64 umax64(u64 a, u64 b) { return a < b ? b : a; }

__global__ void clr_init(const float* __restrict__ seg, float* __restrict__ out) {
  out[0] = seg[0];  // SEG_W = 1.0
}

__global__ __launch_bounds__(192) void clr_loss_kernel(
    const float* __restrict__ pred,   // (3,512,192,78)
    const float* __restrict__ tgt,    // (512,4,78)
    float* __restrict__ out) {
  const int blk  = blockIdx.x;          // stage*512 + b
  const int b    = blk & (kBatch - 1);
  const int tid  = threadIdx.x;
  const int wav  = tid >> 6;
  const int lane = tid & 63;

  __shared__ alignas(16) float s_buf[2][kChunkF];  // double-buffered 64-row chunks
  __shared__ float s_tx[kNpts][kLanes];   // transposed target xs
  __shared__ float s_m [kNpts][kLanes];   // 0/1 validity mask
  __shared__ float s_hdr[kLanes][6];
  __shared__ float s_cost[kLanes][kPriors];
  __shared__ float s_iou[kLanes][kPriors];
  __shared__ u64   s_k3[kLanes][3];       // 3 smallest cost keys per column
  __shared__ int   s_dk[kLanes];          // dyn_k per column (1..3)
  __shared__ float s_sc[3][4];

  const float*  gsrc = pred + (size_t)blk * (kPriors * kD);
  const float4* g4   = (const float4*)gsrc;   // 16B-aligned (row block stride % 16 == 0)

  // ---- stage targets into LDS (transposed xs + mask precompute) ----
  const float* tg = tgt + (size_t)b * kLanes * kD;
  for (int t = tid; t < kLanes * kNpts; t += 192) {
    int j = t / kNpts, k = t - j * kNpts;
    float v = tg[j * kD + 6 + k];
    s_tx[k][j] = v;
    s_m [k][j] = (v >= 0.0f && v < 800.0f) ? 1.0f : 0.0f;
  }
  if (tid < kLanes * 6) {
    int j = tid / 6, c = tid - j * 6;
    s_hdr[j][c] = tg[j * kD + c];
  }
  if (tid < kLanes) {
    s_dk[tid] = 1; s_k3[tid][0] = 0; s_k3[tid][1] = 0; s_k3[tid][2] = 0;
  }

  // ---- stage chunk 0 (coalesced linear float4 copy) ----
  {
    float4* d4 = (float4*)&s_buf[0][0];
#pragma unroll
    for (int it = 0; it < 6; ++it) d4[it * 192 + tid] = g4[it * 192 + tid];
    if (tid < kChunkV4 - 6 * 192) d4[1152 + tid] = g4[1152 + tid];
  }
  __syncthreads();

  bool validL[kLanes];
  int num_t = 0;
#pragma unroll
  for (int j = 0; j < kLanes; ++j) {
    validL[j] = (s_hdr[j][1] == 1.0f);
    num_t += validL[j] ? 1 : 0;
  }
  const bool has_t = num_t > 0;

  // ---- 3 phases: stage next chunk (all waves) + compute own rows (wave p) ----
  float p0 = 0, p1 = 0, p2v = 0, p3v = 0, p4v = 0, p5v = 0;
  float ds0 = 0, ds1 = 0, ds2 = 0, ds3 = 0;
  for (int p = 0; p < 3; ++p) {
    if (p < 2) {
      float4* d4 = (float4*)&s_buf[(p + 1) & 1][0];
      const float4* s4 = g4 + (p + 1) * kChunkV4;
#pragma unroll
      for (int it = 0; it < 6; ++it) d4[it * 192 + tid] = s4[it * 192 + tid];
      if (tid < kChunkV4 - 6 * 192) d4[1152 + tid] = s4[1152 + tid];
    }
    if (wav == p) {
      const float2* L2 = (const float2*)(&s_buf[p & 1][0] + lane * kD);
      float2 h0 = L2[0], h1 = L2[1], h2 = L2[2];
      p0 = h0.x; p1 = h0.y; p2v = h1.x; p3v = h1.y; p4v = h2.x; p5v = h2.y;
      const float4* tx4 = (const float4*)&s_tx[0][0];
      const float4* m4  = (const float4*)&s_m[0][0];
#pragma unroll
      for (int i = 0; i < 36; ++i) {
        float2 a = L2[3 + i];                 // px[2i], px[2i+1]
        float pA = a.x * 799.0f, pB = a.y * 799.0f;
        float4 tA = tx4[2 * i],     mA = m4[2 * i];
        float4 tB = tx4[2 * i + 1], mB = m4[2 * i + 1];
        ds0 = fmaf(mA.x, fabsf(tA.x - pA), ds0);
        ds1 = fmaf(mA.y, fabsf(tA.y - pA), ds1);
        ds2 = fmaf(mA.z, fabsf(tA.z - pA), ds2);
        ds3 = fmaf(mA.w, fabsf(tA.w - pA), ds3);
        ds0 = fmaf(mB.x, fabsf(tB.x - pB), ds0);
        ds1 = fmaf(mB.y, fabsf(tB.y - pB), ds1);
        ds2 = fmaf(mB.z, fabsf(tB.z - pB), ds2);
        ds3 = fmaf(mB.w, fabsf(tB.w - pB), ds3);
      }
    }
    __syncthreads();
  }
  float dsA[kLanes] = {ds0, ds1, ds2, ds3};

  // ---- per-lane scalars: iou/dist closed form; sd, th ----
  float iou[kLanes], dist[kLanes], sd[kLanes], th[kLanes];
  float md = -INFINITY, ms = -INFINITY, mt = -INFINITY;
  const float py = p2v * 319.0f, pxc = p3v * 799.0f;
#pragma unroll
  for (int j = 0; j < kLanes; ++j) {
    float tlen = validL[j] ? s_hdr[j][5] : 0.0f;   // = valid point count
    float ovr = fmaf(tlen, 30.0f, -dsA[j]);
    float uni = fmaf(tlen, 30.0f,  dsA[j]) + 1e-9f;
    iou[j]  = ovr / uni;
    dist[j] = dsA[j] / (tlen + 1e-9f);
    float dy = py - s_hdr[j][2] * 319.0f;
    float dx = pxc - s_hdr[j][3];
    sd[j] = sqrtf(dy * dy + dx * dx);
    th[j] = fabsf(p4v - s_hdr[j][4]) * 180.0f;
    if (validL[j]) {
      md = fmaxf(md, dist[j]);
      ms = fmaxf(ms, sd[j]);
      mt = fmaxf(mt, th[j]);
    }
  }

  // ---- block max reduce for norm_score denominators ----
#pragma unroll
  for (int off = 32; off; off >>= 1) {
    md = fmaxf(md, __shfl_down(md, off, 64));
    ms = fmaxf(ms, __shfl_down(ms, off, 64));
    mt = fmaxf(mt, __shfl_down(mt, off, 64));
  }
  if (lane == 0) { s_sc[wav][0] = md; s_sc[wav][1] = ms; s_sc[wav][2] = mt; }
  __syncthreads();
  md = fmaxf(fmaxf(s_sc[0][0], s_sc[1][0]), s_sc[2][0]);
  ms = fmaxf(fmaxf(s_sc[0][1], s_sc[1][1]), s_sc[2][1]);
  mt = fmaxf(fmaxf(s_sc[0][2], s_sc[1][2]), s_sc[2][2]);
  if (!has_t) { md = 1.0f; ms = 1.0f; mt = 1.0f; }

  // ---- cls_cost ----
  const float sp1  = 1.0f / (1.0f + expf(-p1));
  const float neg1 = -logf(1.0f - sp1 + 1e-12f) * 0.75f * sp1 * sp1;
  const float om1  = 1.0f - sp1;
  const float pos1 = -logf(sp1 + 1e-12f) * 0.25f * om1 * om1;
  const float cls_cost = pos1 - neg1;

  // ---- cost matrix + iou_sg into LDS ----
  float costr[kLanes];
#pragma unroll
  for (int j = 0; j < kLanes; ++j) {
    s_iou[j][tid] = validL[j] ? fmaxf(iou[j], 0.0f) : 0.0f;
    float c;
    if (validL[j]) {
      float a = (1.0f - dist[j] / md) + 0.01f;
      float s = (1.0f - sd[j] / ms) + 0.01f;
      float t = (1.0f - th[j] / mt) + 0.01f;
      float g = a * s * t;
      c = cls_cost - g * g * 3.0f;
    } else {
      c = INFINITY;
    }
    costr[j] = c;
    s_cost[j][tid] = c;
  }
  __syncthreads();

  // ---- 8 selection tasks (4 cost min-3, 4 iou top-4) over 3 waves ----
  for (int t = wav; t < 8; t += 3) {
    const int j = t & 3;
    if (!validL[j]) continue;            // block-uniform: skip invalid columns
    if (t < 4) {
      // 3-reg min-3 butterfly on distinct ordered u64 keys
      float c0 = s_cost[j][lane], c1 = s_cost[j][lane + 64], c2 = s_cost[j][lane + 128];
      u64 k0 = ((u64)ordF(c0) << 32) | (unsigned)lane;
      u64 k1 = ((u64)ordF(c1) << 32) | (unsigned)(lane + 64);
      u64 k2 = ((u64)ordF(c2) << 32) | (unsigned)(lane + 128);
      cswapA(k0, k1); cswapA(k0, k2); cswapA(k1, k2);
#pragma unroll
      for (int off = 1; off < 64; off <<= 1) {
        u64 b0 = __shfl_xor(k0, off), b1 = __shfl_xor(k1, off), b2 = __shfl_xor(k2, off);
        u64 x0 = umin64(k0, b0), y0 = umax64(k0, b0);
        u64 x1 = umin64(k1, b1);
        u64 mc = umin64(k2, b2);
        k0 = x0;
        k2 = umin64(umax64(y0, x1), mc);
        k1 = umin64(y0, x1);
      }
      if (lane == 0) { s_k3[j][0] = k0; s_k3[j][1] = k1; s_k3[j][2] = k2; }
    } else {
      // 4-reg top-4 (descending) butterfly, f32
      float t0 = s_iou[j][lane], t1 = s_iou[j][lane + 64], t2 = s_iou[j][lane + 128];
      float t3 = -1.0f;
      cswapD(t0, t1); cswapD(t0, t2); cswapD(t1, t2);
#pragma unroll
      for (int off = 1; off < 64; off <<= 1) {
        float b0 = __shfl_xor(t0, off), b1 = __shfl_xor(t1, off);
        float b2 = __shfl_xor(t2, off), b3 = __shfl_xor(t3, off);
        float m0 = fmaxf(t0, b3), m1 = fmaxf(t1, b2);
        float m2 = fmaxf(t2, b1), m3 = fmaxf(t3, b0);
        cswapD(m0, m2); cswapD(m1, m3); cswapD(m0, m1); cswapD(m2, m3);
        t0 = m0; t1 = m1; t2 = m2; t3 = m3;
      }
      if (lane == 0) {
        float s = ((t0 + t1) + t2) + t3;   // descending order, matches top_k sum
        int dk = (int)s;                   // iou < 1 strictly => s < 4 => dk <= 3
        if (dk < 1) dk = 1;
        if (dk > 3) dk = 3;
        s_dk[j] = dk;
      }
    }
  }
  __syncthreads();

  // ---- membership: stable-rank < dyn_k  <=>  key <= dyn_k-th smallest key ----
  int Mi[kLanes];
  int msum = 0;
#pragma unroll
  for (int j = 0; j < kLanes; ++j) {
    u64 myk = ((u64)ordF(costr[j]) << 32) | (unsigned)tid;
    Mi[j] = (validL[j] && myk <= s_k3[j][s_dk[j] - 1]) ? 1 : 0;
    msum += Mi[j];
  }

  // argmin over lanes (first-min semantics)
  float amin = costr[0];
  int aidx = 0;
#pragma unroll
  for (int j = 1; j < kLanes; ++j)
    if (costr[j] < amin) { amin = costr[j]; aidx = j; }

  float Mf[kLanes];
#pragma unroll
  for (int j = 0; j < kLanes; ++j) Mf[j] = (float)Mi[j];
  if (msum > 1) {
    Mf[0] = 0.0f;
    Mf[aidx] = 1.0f;
  }

  const float mfsum = Mf[0] + Mf[1] + Mf[2] + Mf[3];
  const int cls_t = (mfsum > 0.0f) ? 1 : 0;

  // ---- focal classification term ----
  const float mx = fmaxf(p0, p1);
  const float e0 = expf(p0 - mx), e1 = expf(p1 - mx);
  const float inv = 1.0f / (e0 + e1);
  const float q = (cls_t ? e1 : e0) * inv + 1e-8f;
  const float omq = 1.0f - q;
  const float focal = -0.25f * omq * omq * logf(q);

  // ---- reg (smooth L1) + iou terms for matched pairs ----
  const float pred_start = fminf(fmaxf(rintf(p2v * 71.0f), 0.0f), 71.0f);
  const float py0 = p2v * 71.0f, py1 = p3v * 799.0f, py2t = p4v * 180.0f, py3 = p5v * 71.0f;
  float regc = 0.0f, iouc = 0.0f;
#pragma unroll
  for (int j = 0; j < kLanes; ++j) {
    if (Mf[j] > 0.0f) {
      float t30 = s_hdr[j][2] * 71.0f;
      float t31 = s_hdr[j][3];
      float t32 = s_hdr[j][4] * 180.0f;
      float tstart = rintf(s_hdr[j][2] * 71.0f);
      float tlp = s_hdr[j][5] - (pred_start - tstart);
      regc += smoothL1(py0 - t30) + smoothL1(py1 - t31) + smoothL1(py2t - t32)
            + smoothL1(py3 - tlp);
      iouc += 1.0f - iou[j];
    }
  }

  // ---- block sum reduce (4 values) ----
  float v0 = mfsum, v1 = focal, v2 = regc, v3 = iouc;
#pragma unroll
  for (int off = 32; off; off >>= 1) {
    v0 += __shfl_down(v0, off, 64);
    v1 += __shfl_down(v1, off, 64);
    v2 += __shfl_down(v2, off, 64);
    v3 += __shfl_down(v3, off, 64);
  }
  __syncthreads();   // s_sc reuse hazard
  if (lane == 0) {
    s_sc[wav][0] = v0; s_sc[wav][1] = v1; s_sc[wav][2] = v2; s_sc[wav][3] = v3;
  }
  __syncthreads();

  if (tid == 0) {
    float nm      = s_sc[0][0] + s_sc[1][0] + s_sc[2][0];
    float cls_sum = s_sc[0][1] + s_sc[1][1] + s_sc[2][1];
    float reg_sum = s_sc[0][2] + s_sc[1][2] + s_sc[2][2];
    float iou_sum = s_sc[0][3] + s_sc[1][3] + s_sc[2][3];

    float cls_term = cls_sum / (has_t ? (float)num_t : 1.0f);
    float reg_term = has_t ? reg_sum / fmaxf(nm * 4.0f, 1.0f) : 0.0f;
    float iou_term = has_t ? iou_sum / fmaxf(nm, 1.0f) : 0.0f;

    float sample = 2.0f * cls_term + 0.2f * reg_term + 2.0f * iou_term;
    atomicAdd(out, sample * (1.0f / (float)(kBatch * kStages)));
  }
}

extern "C" void kernel_launch(void* const* d_in, const int* in_sizes, int n_in,
                              void* d_out, int out_size, void* d_ws, size_t ws_size,
                              hipStream_t stream) {
  const float* pred = (const float*)d_in[0];   // (3,512,192,78) f32
  const float* tgt  = (const float*)d_in[1];   // (512,4,78) f32
  const float* seg  = (const float*)d_in[2];   // scalar f32
  float* out = (float*)d_out;                  // scalar f32

  clr_init<<<1, 1, 0, stream>>>(seg, out);
  clr_loss_kernel<<<kStages * kBatch, 192, 0, stream>>>(pred, tgt, out);
}

// Round 5
// 163.446 us; speedup vs baseline: 1.0128x; 1.0128x over previous
//
#include <hip/hip_runtime.h>
#include <math.h>

constexpr int kNpts   = 72;
constexpr int kPriors = 192;
constexpr int kLanes  = 4;
constexpr int kBatch  = 512;
constexpr int kStages = 3;
constexpr int kD      = 6 + kNpts;            // 78

typedef unsigned long long u64;

__device__ __forceinline__ float smoothL1(float x) {
  float ax = fabsf(x);
  return ax < 1.0f ? 0.5f * x * x : ax - 0.5f;
}

// monotone map float -> uint32 (ascending order preserved, handles +/-inf)
__device__ __forceinline__ unsigned ordF(float f) {
  unsigned b = __float_as_uint(f);
  return (b & 0x80000000u) ? ~b : (b | 0x80000000u);
}

__device__ __forceinline__ void cswapA(u64& a, u64& b) {        // ascending
  if (b < a) { u64 t = a; a = b; b = t; }
}
__device__ __forceinline__ void cswapD(float& a, float& b) {    // descending
  if (b > a) { float t = a; a = b; b = t; }
}
__device__ __forceinline__ u64 umin64(u64 a, u64 b) { return a < b ? a : b; }
__device__ __forceinline__ u64 umax64(u64 a, u64 b) { return a < b ? b : a; }

__global__ void clr_init(const float* __restrict__ seg, float* __restrict__ out) {
  out[0] = seg[0];  // SEG_W = 1.0
}

__global__ __launch_bounds__(384) void clr_loss_kernel(
    const float* __restrict__ pred,   // (3,512,192,78)
    const float* __restrict__ tgt,    // (512,4,78)
    float* __restrict__ out) {
  const int blk  = blockIdx.x;          // stage*512 + b
  const int b    = blk & (kBatch - 1);
  const int tid  = threadIdx.x;         // 0..383
  const int wav  = tid >> 6;            // 0..5
  const int lane = tid & 63;
  const bool prim = (wav < 3);          // waves 0-2: priors 0..191 (front half)
  const int  pid  = prim ? tid : tid - 192;

  __shared__ float  s_tx[kNpts][kLanes];   // transposed target xs
  __shared__ float  s_m [kNpts][kLanes];   // 0/1 validity mask
  __shared__ float  s_hdr[kLanes][6];
  __shared__ float4 s_part[kPriors];       // back-half partial ds
  __shared__ float  s_cost[kLanes][kPriors];
  __shared__ float  s_iou[kLanes][kPriors];
  __shared__ u64    s_k3[kLanes][3];       // 3 smallest cost keys per column
  __shared__ int    s_dk[kLanes];          // dyn_k per column (1..3)
  __shared__ float  s_sc[3][4];

  // ---- stage targets into LDS (transposed xs + mask precompute) ----
  const float* tg = tgt + (size_t)b * kLanes * kD;
  if (tid < kLanes * kNpts) {
    int j = tid / kNpts, k = tid - j * kNpts;
    float v = tg[j * kD + 6 + k];
    s_tx[k][j] = v;
    s_m [k][j] = (v >= 0.0f && v < 800.0f) ? 1.0f : 0.0f;
  }
  if (tid >= 384 - kLanes * 6) {           // last 24 threads (disjoint from above)
    int t = tid - (384 - kLanes * 6);
    int j = t / 6, c = t - j * 6;
    s_hdr[j][c] = tg[j * kD + c];
  }
  if (tid >= 288 && tid < 288 + kLanes) {
    int j = tid - 288;
    s_dk[j] = 1; s_k3[j][0] = 0; s_k3[j][1] = 0; s_k3[j][2] = 0;
  }

  // ---- split row load: front 20 float2 (prim) / back 19 float2 (sec) ----
  const float2* rowv = (const float2*)(pred + ((size_t)blk * kPriors + pid) * kD);
  float2 r[20];
  if (prim) {
#pragma unroll
    for (int i = 0; i < 20; ++i) r[i] = rowv[i];
  } else {
#pragma unroll
    for (int i = 0; i < 19; ++i) r[i] = rowv[20 + i];
  }
  __syncthreads();   // barrier 1: targets staged

  bool validL[kLanes];
  int num_t = 0;
#pragma unroll
  for (int j = 0; j < kLanes; ++j) {
    validL[j] = (s_hdr[j][1] == 1.0f);
    num_t += validL[j] ? 1 : 0;
  }
  const bool has_t = num_t > 0;

  // ---- partial ds over my px range ----
  float ds0 = 0, ds1 = 0, ds2 = 0, ds3 = 0;
  float p0 = 0, p1 = 0, p2v = 0, p3v = 0, p4v = 0, p5v = 0;
  const float4* tx4 = (const float4*)&s_tx[0][0];
  const float4* m4  = (const float4*)&s_m[0][0];
  if (prim) {
    p0 = r[0].x; p1 = r[0].y; p2v = r[1].x; p3v = r[1].y; p4v = r[2].x; p5v = r[2].y;
#pragma unroll
    for (int i = 0; i < 17; ++i) {         // k = 0..33
      float pA = r[3 + i].x * 799.0f, pB = r[3 + i].y * 799.0f;
      float4 tA = tx4[2 * i],     mA = m4[2 * i];
      float4 tB = tx4[2 * i + 1], mB = m4[2 * i + 1];
      ds0 = fmaf(mA.x, fabsf(tA.x - pA), ds0);
      ds1 = fmaf(mA.y, fabsf(tA.y - pA), ds1);
      ds2 = fmaf(mA.z, fabsf(tA.z - pA), ds2);
      ds3 = fmaf(mA.w, fabsf(tA.w - pA), ds3);
      ds0 = fmaf(mB.x, fabsf(tB.x - pB), ds0);
      ds1 = fmaf(mB.y, fabsf(tB.y - pB), ds1);
      ds2 = fmaf(mB.z, fabsf(tB.z - pB), ds2);
      ds3 = fmaf(mB.w, fabsf(tB.w - pB), ds3);
    }
  } else {
#pragma unroll
    for (int i = 0; i < 19; ++i) {         // k = 34..71
      float pA = r[i].x * 799.0f, pB = r[i].y * 799.0f;
      int k = 34 + 2 * i;
      float4 tA = tx4[k],     mA = m4[k];
      float4 tB = tx4[k + 1], mB = m4[k + 1];
      ds0 = fmaf(mA.x, fabsf(tA.x - pA), ds0);
      ds1 = fmaf(mA.y, fabsf(tA.y - pA), ds1);
      ds2 = fmaf(mA.z, fabsf(tA.z - pA), ds2);
      ds3 = fmaf(mA.w, fabsf(tA.w - pA), ds3);
      ds0 = fmaf(mB.x, fabsf(tB.x - pB), ds0);
      ds1 = fmaf(mB.y, fabsf(tB.y - pB), ds1);
      ds2 = fmaf(mB.z, fabsf(tB.z - pB), ds2);
      ds3 = fmaf(mB.w, fabsf(tB.w - pB), ds3);
    }
    s_part[pid] = make_float4(ds0, ds1, ds2, ds3);
  }
  __syncthreads();   // barrier 2: partials ready

  // ---- per-lane scalars (prim only): iou/dist closed form; sd, th ----
  float iou[kLanes], dist[kLanes], sd[kLanes], th[kLanes], costr[kLanes];
  float md = -INFINITY, ms = -INFINITY, mt = -INFINITY;
  if (prim) {
    float4 q = s_part[pid];
    float dsA[kLanes] = {ds0 + q.x, ds1 + q.y, ds2 + q.z, ds3 + q.w};
    const float py = p2v * 319.0f, pxc = p3v * 799.0f;
#pragma unroll
    for (int j = 0; j < kLanes; ++j) {
      float tlen = validL[j] ? s_hdr[j][5] : 0.0f;   // = valid point count
      float ovr = fmaf(tlen, 30.0f, -dsA[j]);
      float uni = fmaf(tlen, 30.0f,  dsA[j]) + 1e-9f;
      iou[j]  = ovr / uni;
      dist[j] = dsA[j] / (tlen + 1e-9f);
      float dy = py - s_hdr[j][2] * 319.0f;
      float dx = pxc - s_hdr[j][3];
      sd[j] = sqrtf(dy * dy + dx * dx);
      th[j] = fabsf(p4v - s_hdr[j][4]) * 180.0f;
      if (validL[j]) {
        md = fmaxf(md, dist[j]);
        ms = fmaxf(ms, sd[j]);
        mt = fmaxf(mt, th[j]);
      }
    }
#pragma unroll
    for (int off = 32; off; off >>= 1) {
      md = fmaxf(md, __shfl_down(md, off, 64));
      ms = fmaxf(ms, __shfl_down(ms, off, 64));
      mt = fmaxf(mt, __shfl_down(mt, off, 64));
    }
    if (lane == 0) { s_sc[wav][0] = md; s_sc[wav][1] = ms; s_sc[wav][2] = mt; }
  }
  __syncthreads();   // barrier 3: maxes ready

  if (prim) {
    md = fmaxf(fmaxf(s_sc[0][0], s_sc[1][0]), s_sc[2][0]);
    ms = fmaxf(fmaxf(s_sc[0][1], s_sc[1][1]), s_sc[2][1]);
    mt = fmaxf(fmaxf(s_sc[0][2], s_sc[1][2]), s_sc[2][2]);
    if (!has_t) { md = 1.0f; ms = 1.0f; mt = 1.0f; }

    // cls_cost
    const float sp1  = 1.0f / (1.0f + expf(-p1));
    const float neg1 = -logf(1.0f - sp1 + 1e-12f) * 0.75f * sp1 * sp1;
    const float om1  = 1.0f - sp1;
    const float pos1 = -logf(sp1 + 1e-12f) * 0.25f * om1 * om1;
    const float cls_cost = pos1 - neg1;

    // cost matrix + iou_sg into LDS
#pragma unroll
    for (int j = 0; j < kLanes; ++j) {
      s_iou[j][pid] = validL[j] ? fmaxf(iou[j], 0.0f) : 0.0f;
      float c;
      if (validL[j]) {
        float a = (1.0f - dist[j] / md) + 0.01f;
        float s = (1.0f - sd[j] / ms) + 0.01f;
        float t = (1.0f - th[j] / mt) + 0.01f;
        float g = a * s * t;
        c = cls_cost - g * g * 3.0f;
      } else {
        c = INFINITY;
      }
      costr[j] = c;
      s_cost[j][pid] = c;
    }
  }
  __syncthreads();   // barrier 4: cost/iou matrices ready

  // ---- 8 selection tasks (4 cost min-3, 4 iou top-4) over 6 waves ----
  for (int t = wav; t < 8; t += 6) {
    const int j = t & 3;
    if (!validL[j]) continue;            // block-uniform
    if (t < 4) {
      // 3-reg min-3 butterfly on distinct ordered u64 keys
      float c0 = s_cost[j][lane], c1 = s_cost[j][lane + 64], c2 = s_cost[j][lane + 128];
      u64 k0 = ((u64)ordF(c0) << 32) | (unsigned)lane;
      u64 k1 = ((u64)ordF(c1) << 32) | (unsigned)(lane + 64);
      u64 k2 = ((u64)ordF(c2) << 32) | (unsigned)(lane + 128);
      cswapA(k0, k1); cswapA(k0, k2); cswapA(k1, k2);
#pragma unroll
      for (int off = 1; off < 64; off <<= 1) {
        u64 b0 = __shfl_xor(k0, off), b1 = __shfl_xor(k1, off), b2 = __shfl_xor(k2, off);
        u64 x0 = umin64(k0, b0), y0 = umax64(k0, b0);
        u64 x1 = umin64(k1, b1);
        u64 mc = umin64(k2, b2);
        k0 = x0;
        k2 = umin64(umax64(y0, x1), mc);
        k1 = umin64(y0, x1);
      }
      if (lane == 0) { s_k3[j][0] = k0; s_k3[j][1] = k1; s_k3[j][2] = k2; }
    } else {
      // 4-reg top-4 (descending) butterfly, f32
      float t0 = s_iou[j][lane], t1 = s_iou[j][lane + 64], t2 = s_iou[j][lane + 128];
      float t3 = -1.0f;
      cswapD(t0, t1); cswapD(t0, t2); cswapD(t1, t2);
#pragma unroll
      for (int off = 1; off < 64; off <<= 1) {
        float b0 = __shfl_xor(t0, off), b1 = __shfl_xor(t1, off);
        float b2 = __shfl_xor(t2, off), b3 = __shfl_xor(t3, off);
        float m0 = fmaxf(t0, b3), m1 = fmaxf(t1, b2);
        float m2 = fmaxf(t2, b1), m3 = fmaxf(t3, b0);
        cswapD(m0, m2); cswapD(m1, m3); cswapD(m0, m1); cswapD(m2, m3);
        t0 = m0; t1 = m1; t2 = m2; t3 = m3;
      }
      if (lane == 0) {
        float s = ((t0 + t1) + t2) + t3;   // descending order, matches top_k sum
        int dk = (int)s;                   // iou < 1 strictly => s < 4 => dk <= 3
        if (dk < 1) dk = 1;
        if (dk > 3) dk = 3;
        s_dk[j] = dk;
      }
    }
  }
  __syncthreads();   // barrier 5: thresholds ready

  float v0 = 0, v1 = 0, v2 = 0, v3 = 0;
  if (prim) {
    // membership: stable-rank < dyn_k  <=>  key <= dyn_k-th smallest key
    int Mi[kLanes];
    int msum = 0;
#pragma unroll
    for (int j = 0; j < kLanes; ++j) {
      u64 myk = ((u64)ordF(costr[j]) << 32) | (unsigned)pid;
      Mi[j] = (validL[j] && myk <= s_k3[j][s_dk[j] - 1]) ? 1 : 0;
      msum += Mi[j];
    }

    // argmin over lanes (first-min semantics)
    float amin = costr[0];
    int aidx = 0;
#pragma unroll
    for (int j = 1; j < kLanes; ++j)
      if (costr[j] < amin) { amin = costr[j]; aidx = j; }

    float Mf[kLanes];
#pragma unroll
    for (int j = 0; j < kLanes; ++j) Mf[j] = (float)Mi[j];
    if (msum > 1) {
      Mf[0] = 0.0f;
      Mf[aidx] = 1.0f;
    }

    const float mfsum = Mf[0] + Mf[1] + Mf[2] + Mf[3];
    const int cls_t = (mfsum > 0.0f) ? 1 : 0;

    // focal classification term
    const float mx = fmaxf(p0, p1);
    const float e0 = expf(p0 - mx), e1 = expf(p1 - mx);
    const float inv = 1.0f / (e0 + e1);
    const float q = (cls_t ? e1 : e0) * inv + 1e-8f;
    const float omq = 1.0f - q;
    const float focal = -0.25f * omq * omq * logf(q);

    // reg (smooth L1) + iou terms for matched pairs
    const float pred_start = fminf(fmaxf(rintf(p2v * 71.0f), 0.0f), 71.0f);
    const float py0 = p2v * 71.0f, py1 = p3v * 799.0f, py2t = p4v * 180.0f, py3 = p5v * 71.0f;
    float regc = 0.0f, iouc = 0.0f;
#pragma unroll
    for (int j = 0; j < kLanes; ++j) {
      if (Mf[j] > 0.0f) {
        float t30 = s_hdr[j][2] * 71.0f;
        float t31 = s_hdr[j][3];
        float t32 = s_hdr[j][4] * 180.0f;
        float tstart = rintf(s_hdr[j][2] * 71.0f);
        float tlp = s_hdr[j][5] - (pred_start - tstart);
        regc += smoothL1(py0 - t30) + smoothL1(py1 - t31) + smoothL1(py2t - t32)
              + smoothL1(py3 - tlp);
        iouc += 1.0f - iou[j];
      }
    }

    v0 = mfsum; v1 = focal; v2 = regc; v3 = iouc;
#pragma unroll
    for (int off = 32; off; off >>= 1) {
      v0 += __shfl_down(v0, off, 64);
      v1 += __shfl_down(v1, off, 64);
      v2 += __shfl_down(v2, off, 64);
      v3 += __shfl_down(v3, off, 64);
    }
    if (lane == 0) {
      s_sc[wav][0] = v0; s_sc[wav][1] = v1; s_sc[wav][2] = v2; s_sc[wav][3] = v3;
    }
  }
  __syncthreads();   // barrier 6: partial sums ready

  if (tid == 0) {
    float nm      = s_sc[0][0] + s_sc[1][0] + s_sc[2][0];
    float cls_sum = s_sc[0][1] + s_sc[1][1] + s_sc[2][1];
    float reg_sum = s_sc[0][2] + s_sc[1][2] + s_sc[2][2];
    float iou_sum = s_sc[0][3] + s_sc[1][3] + s_sc[2][3];

    float cls_term = cls_sum / (has_t ? (float)num_t : 1.0f);
    float reg_term = has_t ? reg_sum / fmaxf(nm * 4.0f, 1.0f) : 0.0f;
    float iou_term = has_t ? iou_sum / fmaxf(nm, 1.0f) : 0.0f;

    float sample = 2.0f * cls_term + 0.2f * reg_term + 2.0f * iou_term;
    atomicAdd(out, sample * (1.0f / (float)(kBatch * kStages)));
  }
}

extern "C" void kernel_launch(void* const* d_in, const int* in_sizes, int n_in,
                              void* d_out, int out_size, void* d_ws, size_t ws_size,
                              hipStream_t stream) {
  const float* pred = (const float*)d_in[0];   // (3,512,192,78) f32
  const float* tgt  = (const float*)d_in[1];   // (512,4,78) f32
  const float* seg  = (const float*)d_in[2];   // scalar f32
  float* out = (float*)d_out;                  // scalar f32

  clr_init<<<1, 1, 0, stream>>>(seg, out);
  clr_loss_kernel<<<kStages * kBatch, 384, 0, stream>>>(pred, tgt, out);
}

// Round 6
// 146.381 us; speedup vs baseline: 1.1309x; 1.1166x over previous
//
#include <hip/hip_runtime.h>
#include <math.h>

constexpr int kNpts   = 72;
constexpr int kPriors = 192;
constexpr int kLanes  = 4;
constexpr int kBatch  = 512;
constexpr int kStages = 3;
constexpr int kD      = 6 + kNpts;  // 78
constexpr int kBlocks = kStages * kBatch;   // 1536

typedef unsigned long long u64;

__device__ __forceinline__ float smoothL1(float x) {
  float ax = fabsf(x);
  return ax < 1.0f ? 0.5f * x * x : ax - 0.5f;
}

// monotone map float -> uint32 (ascending order preserved, handles +/-inf)
__device__ __forceinline__ unsigned ordF(float f) {
  unsigned b = __float_as_uint(f);
  return (b & 0x80000000u) ? ~b : (b | 0x80000000u);
}

__device__ __forceinline__ void cswapA(u64& a, u64& b) {        // ascending
  if (b < a) { u64 t = a; a = b; b = t; }
}
__device__ __forceinline__ void cswapD(float& a, float& b) {    // descending
  if (b > a) { float t = a; a = b; b = t; }
}
__device__ __forceinline__ u64 umin64(u64 a, u64 b) { return a < b ? a : b; }
__device__ __forceinline__ u64 umax64(u64 a, u64 b) { return a < b ? b : a; }

__global__ __launch_bounds__(192) void clr_loss_kernel(
    const float* __restrict__ pred,   // (3,512,192,78)
    const float* __restrict__ tgt,    // (512,4,78)
    float* __restrict__ partial) {    // (1536,) per-block weighted sample
  const int blk  = blockIdx.x;          // stage*512 + b
  const int b    = blk & (kBatch - 1);
  const int tid  = threadIdx.x;         // one prior per thread
  const int wav  = tid >> 6;
  const int lane = tid & 63;

  __shared__ float s_tx[kNpts][kLanes];   // transposed target xs
  __shared__ float s_m [kNpts][kLanes];   // 0/1 validity mask
  __shared__ float s_hdr[kLanes][6];
  __shared__ float s_cost[kLanes][kPriors];
  __shared__ float s_iou[kLanes][kPriors];
  __shared__ u64   s_k3[kLanes][3];       // 3 smallest cost keys per column
  __shared__ int   s_dk[kLanes];          // dyn_k per column (1..3)
  __shared__ float s_sc[3][4];

  // ---- stage targets into LDS (transposed xs + mask precompute) ----
  const float* tg = tgt + (size_t)b * kLanes * kD;
  for (int t = tid; t < kLanes * kNpts; t += 192) {
    int j = t / kNpts, k = t - j * kNpts;
    float v = tg[j * kD + 6 + k];
    s_tx[k][j] = v;
    s_m [k][j] = (v >= 0.0f && v < 800.0f) ? 1.0f : 0.0f;
  }
  if (tid < kLanes * 6) {
    int j = tid / 6, c = tid - j * 6;
    s_hdr[j][c] = tg[j * kD + c];
  }
  if (tid >= 64 && tid < 64 + kLanes) {
    int j = tid - 64;
    s_dk[j] = 1; s_k3[j][0] = 0; s_k3[j][1] = 0; s_k3[j][2] = 0;
  }

  // ---- burst-load my prior row (39 x float2, 8B aligned) ----
  const float*  pr   = pred + ((size_t)blk * kPriors + tid) * kD;
  const float2* rowv = (const float2*)pr;
  float2 h0 = rowv[0], h1 = rowv[1], h2 = rowv[2];
  float px[kNpts];
#pragma unroll
  for (int q = 0; q < 36; ++q) {
    float2 v = rowv[3 + q];
    px[2 * q]     = v.x * 799.0f;
    px[2 * q + 1] = v.y * 799.0f;
  }
  const float p0 = h0.x, p1 = h0.y, p2 = h1.x, p3 = h1.y, p4 = h2.x, p5 = h2.y;

  __syncthreads();

  bool validL[kLanes];
  int num_t = 0;
#pragma unroll
  for (int j = 0; j < kLanes; ++j) {
    validL[j] = (s_hdr[j][1] == 1.0f);
    num_t += validL[j] ? 1 : 0;
  }
  const bool has_t = num_t > 0;

  // ---- collapsed streaming pass: only dsum needed (2 VALU/elem) ----
  float ds[kLanes] = {0.0f, 0.0f, 0.0f, 0.0f};
  {
    const float4* tx4 = (const float4*)&s_tx[0][0];
    const float4* m4  = (const float4*)&s_m[0][0];
#pragma unroll
    for (int k = 0; k < kNpts; ++k) {
      float4 t = tx4[k];
      float4 m = m4[k];
      float p = px[k];
      ds[0] = fmaf(m.x, fabsf(t.x - p), ds[0]);
      ds[1] = fmaf(m.y, fabsf(t.y - p), ds[1]);
      ds[2] = fmaf(m.z, fabsf(t.z - p), ds[2]);
      ds[3] = fmaf(m.w, fabsf(t.w - p), ds[3]);
    }
  }

  // ---- per-lane scalars: iou/dist closed form; sd, th ----
  float iou[kLanes], dist[kLanes], sd[kLanes], th[kLanes];
  float md = -INFINITY, ms = -INFINITY, mt = -INFINITY;
  const float py = p2 * 319.0f, pxc = p3 * 799.0f;
#pragma unroll
  for (int j = 0; j < kLanes; ++j) {
    float tlen = validL[j] ? s_hdr[j][5] : 0.0f;   // = valid point count
    float ovr = fmaf(tlen, 30.0f, -ds[j]);
    float uni = fmaf(tlen, 30.0f,  ds[j]) + 1e-9f;
    iou[j]  = ovr / uni;
    dist[j] = ds[j] / (tlen + 1e-9f);
    float dy = py - s_hdr[j][2] * 319.0f;
    float dx = pxc - s_hdr[j][3];
    sd[j] = sqrtf(dy * dy + dx * dx);
    th[j] = fabsf(p4 - s_hdr[j][4]) * 180.0f;
    if (validL[j]) {
      md = fmaxf(md, dist[j]);
      ms = fmaxf(ms, sd[j]);
      mt = fmaxf(mt, th[j]);
    }
  }

  // ---- block max reduce for norm_score denominators ----
#pragma unroll
  for (int off = 32; off; off >>= 1) {
    md = fmaxf(md, __shfl_down(md, off, 64));
    ms = fmaxf(ms, __shfl_down(ms, off, 64));
    mt = fmaxf(mt, __shfl_down(mt, off, 64));
  }
  if (lane == 0) { s_sc[wav][0] = md; s_sc[wav][1] = ms; s_sc[wav][2] = mt; }
  __syncthreads();
  md = fmaxf(fmaxf(s_sc[0][0], s_sc[1][0]), s_sc[2][0]);
  ms = fmaxf(fmaxf(s_sc[0][1], s_sc[1][1]), s_sc[2][1]);
  mt = fmaxf(fmaxf(s_sc[0][2], s_sc[1][2]), s_sc[2][2]);
  if (!has_t) { md = 1.0f; ms = 1.0f; mt = 1.0f; }

  // ---- cls_cost ----
  const float sp1  = 1.0f / (1.0f + expf(-p1));
  const float neg1 = -logf(1.0f - sp1 + 1e-12f) * 0.75f * sp1 * sp1;
  const float om1  = 1.0f - sp1;
  const float pos1 = -logf(sp1 + 1e-12f) * 0.25f * om1 * om1;
  const float cls_cost = pos1 - neg1;

  // ---- cost matrix + iou_sg into LDS ----
  float costr[kLanes];
#pragma unroll
  for (int j = 0; j < kLanes; ++j) {
    s_iou[j][tid] = validL[j] ? fmaxf(iou[j], 0.0f) : 0.0f;
    float c;
    if (validL[j]) {
      float a = (1.0f - dist[j] / md) + 0.01f;
      float s = (1.0f - sd[j] / ms) + 0.01f;
      float t = (1.0f - th[j] / mt) + 0.01f;
      float g = a * s * t;
      c = cls_cost - g * g * 3.0f;
    } else {
      c = INFINITY;
    }
    costr[j] = c;
    s_cost[j][tid] = c;
  }
  __syncthreads();

  // ---- 8 selection tasks (4 cost min-3, 4 iou top-4) over 3 waves ----
  for (int t = wav; t < 8; t += 3) {
    const int j = t & 3;
    if (!validL[j]) continue;            // block-uniform
    if (t < 4) {
      // 3-reg min-3 butterfly on distinct ordered u64 keys
      float c0 = s_cost[j][lane], c1 = s_cost[j][lane + 64], c2 = s_cost[j][lane + 128];
      u64 k0 = ((u64)ordF(c0) << 32) | (unsigned)lane;
      u64 k1 = ((u64)ordF(c1) << 32) | (unsigned)(lane + 64);
      u64 k2 = ((u64)ordF(c2) << 32) | (unsigned)(lane + 128);
      cswapA(k0, k1); cswapA(k0, k2); cswapA(k1, k2);
#pragma unroll
      for (int off = 1; off < 64; off <<= 1) {
        u64 b0 = __shfl_xor(k0, off), b1 = __shfl_xor(k1, off), b2 = __shfl_xor(k2, off);
        u64 x0 = umin64(k0, b0), y0 = umax64(k0, b0);
        u64 x1 = umin64(k1, b1);
        u64 mc = umin64(k2, b2);
        k0 = x0;
        k2 = umin64(umax64(y0, x1), mc);
        k1 = umin64(y0, x1);
      }
      if (lane == 0) { s_k3[j][0] = k0; s_k3[j][1] = k1; s_k3[j][2] = k2; }
    } else {
      // 4-reg top-4 (descending) butterfly, f32
      float t0 = s_iou[j][lane], t1 = s_iou[j][lane + 64], t2 = s_iou[j][lane + 128];
      float t3 = -1.0f;
      cswapD(t0, t1); cswapD(t0, t2); cswapD(t1, t2);
#pragma unroll
      for (int off = 1; off < 64; off <<= 1) {
        float b0 = __shfl_xor(t0, off), b1 = __shfl_xor(t1, off);
        float b2 = __shfl_xor(t2, off), b3 = __shfl_xor(t3, off);
        float m0 = fmaxf(t0, b3), m1 = fmaxf(t1, b2);
        float m2 = fmaxf(t2, b1), m3 = fmaxf(t3, b0);
        cswapD(m0, m2); cswapD(m1, m3); cswapD(m0, m1); cswapD(m2, m3);
        t0 = m0; t1 = m1; t2 = m2; t3 = m3;
      }
      if (lane == 0) {
        float s = ((t0 + t1) + t2) + t3;   // descending order, matches top_k sum
        int dk = (int)s;                   // iou < 1 strictly => s < 4 => dk <= 3
        if (dk < 1) dk = 1;
        if (dk > 3) dk = 3;
        s_dk[j] = dk;
      }
    }
  }
  __syncthreads();

  // ---- membership: stable-rank < dyn_k  <=>  key <= dyn_k-th smallest key ----
  int Mi[kLanes];
  int msum = 0;
#pragma unroll
  for (int j = 0; j < kLanes; ++j) {
    u64 myk = ((u64)ordF(costr[j]) << 32) | (unsigned)tid;
    Mi[j] = (validL[j] && myk <= s_k3[j][s_dk[j] - 1]) ? 1 : 0;
    msum += Mi[j];
  }

  // argmin over lanes (first-min semantics)
  float amin = costr[0];
  int aidx = 0;
#pragma unroll
  for (int j = 1; j < kLanes; ++j)
    if (costr[j] < amin) { amin = costr[j]; aidx = j; }

  float Mf[kLanes];
#pragma unroll
  for (int j = 0; j < kLanes; ++j) Mf[j] = (float)Mi[j];
  if (msum > 1) {
    Mf[0] = 0.0f;
    Mf[aidx] = 1.0f;
  }

  const float mfsum = Mf[0] + Mf[1] + Mf[2] + Mf[3];
  const int cls_t = (mfsum > 0.0f) ? 1 : 0;

  // ---- focal classification term ----
  const float mx = fmaxf(p0, p1);
  const float e0 = expf(p0 - mx), e1 = expf(p1 - mx);
  const float inv = 1.0f / (e0 + e1);
  const float q = (cls_t ? e1 : e0) * inv + 1e-8f;
  const float omq = 1.0f - q;
  const float focal = -0.25f * omq * omq * logf(q);

  // ---- reg (smooth L1) + iou terms for matched pairs ----
  const float pred_start = fminf(fmaxf(rintf(p2 * 71.0f), 0.0f), 71.0f);
  const float py0 = p2 * 71.0f, py1 = p3 * 799.0f, py2t = p4 * 180.0f, py3 = p5 * 71.0f;
  float regc = 0.0f, iouc = 0.0f;
#pragma unroll
  for (int j = 0; j < kLanes; ++j) {
    if (Mf[j] > 0.0f) {
      float t30 = s_hdr[j][2] * 71.0f;
      float t31 = s_hdr[j][3];
      float t32 = s_hdr[j][4] * 180.0f;
      float tstart = rintf(s_hdr[j][2] * 71.0f);
      float tlp = s_hdr[j][5] - (pred_start - tstart);
      regc += smoothL1(py0 - t30) + smoothL1(py1 - t31) + smoothL1(py2t - t32)
            + smoothL1(py3 - tlp);
      iouc += 1.0f - iou[j];
    }
  }

  // ---- block sum reduce (4 values) ----
  float v0 = mfsum, v1 = focal, v2 = regc, v3 = iouc;
#pragma unroll
  for (int off = 32; off; off >>= 1) {
    v0 += __shfl_down(v0, off, 64);
    v1 += __shfl_down(v1, off, 64);
    v2 += __shfl_down(v2, off, 64);
    v3 += __shfl_down(v3, off, 64);
  }
  __syncthreads();   // s_sc reuse hazard
  if (lane == 0) {
    s_sc[wav][0] = v0; s_sc[wav][1] = v1; s_sc[wav][2] = v2; s_sc[wav][3] = v3;
  }
  __syncthreads();

  if (tid == 0) {
    float nm      = s_sc[0][0] + s_sc[1][0] + s_sc[2][0];
    float cls_sum = s_sc[0][1] + s_sc[1][1] + s_sc[2][1];
    float reg_sum = s_sc[0][2] + s_sc[1][2] + s_sc[2][2];
    float iou_sum = s_sc[0][3] + s_sc[1][3] + s_sc[2][3];

    float cls_term = cls_sum / (has_t ? (float)num_t : 1.0f);
    float reg_term = has_t ? reg_sum / fmaxf(nm * 4.0f, 1.0f) : 0.0f;
    float iou_term = has_t ? iou_sum / fmaxf(nm, 1.0f) : 0.0f;

    // plain store — no same-address atomic contention
    partial[blk] = 2.0f * cls_term + 0.2f * reg_term + 2.0f * iou_term;
  }
}

__global__ __launch_bounds__(256) void clr_reduce(
    const float* __restrict__ partial,   // (1536,)
    const float* __restrict__ seg,
    float* __restrict__ out) {
  const int tid  = threadIdx.x;
  const int wav  = tid >> 6;
  const int lane = tid & 63;
  __shared__ float sc[4];

  float s = 0.0f;
#pragma unroll
  for (int i = 0; i < kBlocks / 256; ++i) s += partial[tid + 256 * i];
#pragma unroll
  for (int off = 32; off; off >>= 1) s += __shfl_down(s, off, 64);
  if (lane == 0) sc[wav] = s;
  __syncthreads();
  if (tid == 0) {
    float tot = ((sc[0] + sc[1]) + sc[2]) + sc[3];
    out[0] = tot * (1.0f / (float)kBlocks) + seg[0];
  }
}

extern "C" void kernel_launch(void* const* d_in, const int* in_sizes, int n_in,
                              void* d_out, int out_size, void* d_ws, size_t ws_size,
                              hipStream_t stream) {
  const float* pred = (const float*)d_in[0];   // (3,512,192,78) f32
  const float* tgt  = (const float*)d_in[1];   // (512,4,78) f32
  const float* seg  = (const float*)d_in[2];   // scalar f32
  float* out     = (float*)d_out;              // scalar f32
  float* partial = (float*)d_ws;               // 1536 floats of scratch

  clr_loss_kernel<<<kBlocks, 192, 0, stream>>>(pred, tgt, partial);
  clr_reduce<<<1, 256, 0, stream>>>(partial, seg, out);
}